// Round 3
// baseline (1590.908 us; speedup 1.0000x reference)
//
#include <hip/hip_runtime.h>
#include <hip/hip_fp16.h>

typedef _Float16 f16;
typedef _Float16 f16x8 __attribute__((ext_vector_type(8)));
typedef _Float16 f16x4 __attribute__((ext_vector_type(4)));
typedef float f32x4 __attribute__((ext_vector_type(4)));

#define NH 12
#define NWIN 4096
// tokens per window = 64, head dim = 32, DIM = 384, qkv N = 1152

__device__ __forceinline__ void gload16(const void* g, void* l) {
  __builtin_amdgcn_global_load_lds(
      (const __attribute__((address_space(1))) void*)g,
      (__attribute__((address_space(3))) void*)l, 16, 0, 0);
}

// ---------------- prep kernels ----------------

__global__ __launch_bounds__(256) void k_cvt_x(const float* __restrict__ in,
                                               f16* __restrict__ out, long n4) {
  long i = (long)blockIdx.x * 256 + threadIdx.x;
  long stride = (long)gridDim.x * 256;
  for (; i < n4; i += stride) {
    float4 v = ((const float4*)in)[i];
    f16x4 o = {(f16)v.x, (f16)v.y, (f16)v.z, (f16)v.w};
    ((f16x4*)out)[i] = o;
  }
}

// out[n*K + k] = in[k*N + n]  (cast to f16)
__global__ __launch_bounds__(256) void k_transpose(const float* __restrict__ in,
                                                   f16* __restrict__ out, int K, int N) {
  long i = (long)blockIdx.x * 256 + threadIdx.x;
  if (i >= (long)K * N) return;
  int n = (int)(i / K);
  int k = (int)(i - (long)n * K);
  out[i] = (f16)in[(long)k * N + n];
}

// continuous position bias: bias[h][p] = 16*sigmoid( MLP(table[rel_pos_index[p]]) . w2[:,h] )
__global__ __launch_bounds__(64) void k_cpb(const float* __restrict__ table,
                                            const int* __restrict__ ridx,
                                            const float* __restrict__ w1,
                                            const float* __restrict__ b1,
                                            const float* __restrict__ w2,
                                            float* __restrict__ biasout) {
  int p = blockIdx.x * 64 + threadIdx.x;  // 0..4095
  int idx = ridx[p];
  float t0 = table[idx * 2], t1 = table[idx * 2 + 1];
  float acc[NH] = {};
  for (int u = 0; u < 512; u++) {
    float hv = fmaxf(t0 * w1[u] + t1 * w1[512 + u] + b1[u], 0.f);
#pragma unroll
    for (int h = 0; h < NH; h++) acc[h] += hv * w2[u * NH + h];
  }
  for (int h = 0; h < NH; h++) biasout[h * 4096 + p] = 16.f / (1.f + __expf(-acc[h]));
}

// ---------------- persistent GEMM: C[M x N] = A[M x K] * Bt[N x K]^T + bias -------
// Each block owns TPB output tiles (ym-major, xn fastest -> A-panel reused across
// NXB consecutive tiles). The 2-phase double-buffer pipeline flows ACROSS tile
// boundaries: during tile t's last k-step we stage tile t+1's k=0 chunk, so the
// prologue drain is paid once per block and the register-only epilogue overlaps
// the next tile's in-flight loads. grid = 768 = 3 blocks/CU (pinned below).
// MODE 0: qkv gemm (N=1152), f16 scatter out to [3][b*12+h][64][32]
// MODE 1: proj gemm (N=384), fp32 out row-major [M][384]
template <int MODE, int NXB, int TPB>
__global__ __launch_bounds__(256, 3) void k_gemm(const f16* __restrict__ A,
                                                 const f16* __restrict__ Bt,
                                                 const float* __restrict__ bias,
                                                 void* __restrict__ out, int K) {
  __shared__ f16 smem[2 * 8192];  // [buf][As 4096 f16 | Bs 4096 f16]
  const int tid = threadIdx.x;
  const int lane = tid & 63, wid = tid >> 6;
  const int wm = wid & 1, wn = wid >> 1;
  const int quad = lane >> 4, col0 = lane & 15;

  // staging geometry: wave wid covers rows [wid*32, wid*32+32), 4 lanes/row
  const int r0 = wid * 32 + (lane >> 2);
  const int co0 = (lane & 3) * 8;
  const int ldsoff = (wid * 32) * 32;

  const int lin0 = blockIdx.x * TPB;

  auto rows_of = [&](int t, long& ar, long& br) {
    int lin = lin0 + t;
    int ym = lin / NXB;  // compile-time NXB -> magic-mul
    int xn = lin - ym * NXB;
    ar = (long)ym * 128;
    br = (long)xn * 128;
  };

  auto stage = [&](int buf, long ar, long br, int kk) {
#pragma unroll
    for (int j = 0; j < 2; j++) {
      gload16(A + (ar + r0 + j * 16) * K + co0 + kk,
              smem + buf * 8192 + ldsoff + j * 16 * 32);
      gload16(Bt + (br + r0 + j * 16) * K + co0 + kk,
              smem + buf * 8192 + 4096 + ldsoff + j * 16 * 32);
    }
  };

  f32x4 acc[4][4] = {};
  long ar, br;
  rows_of(0, ar, br);
  stage(0, ar, br, 0);
  __syncthreads();  // prologue drain (full latency, paid once per block)
  int cur = 0;

#pragma unroll 1
  for (int t = 0; t < TPB; t++) {
    rows_of(t, ar, br);
#pragma unroll 1
    for (int kk = 0; kk < K; kk += 32) {
      if (kk + 32 < K) {
        stage(cur ^ 1, ar, br, kk + 32);
      } else if (t + 1 < TPB) {
        long a2, b2;
        rows_of(t + 1, a2, b2);
        stage(cur ^ 1, a2, b2, 0);  // cross-tile prefetch: pipeline never drains
      }
      const f16* As = smem + cur * 8192;
      const f16* Bs = As + 4096;
      f16x8 am[4], bn[4];
#pragma unroll
      for (int tt = 0; tt < 4; tt++) {
        am[tt] = *(const f16x8*)&As[(wm * 64 + tt * 16 + col0) * 32 + quad * 8];
        bn[tt] = *(const f16x8*)&Bs[(wn * 64 + tt * 16 + col0) * 32 + quad * 8];
      }
#pragma unroll
      for (int mt = 0; mt < 4; mt++)
#pragma unroll
        for (int nt = 0; nt < 4; nt++)
          acc[mt][nt] = __builtin_amdgcn_mfma_f32_16x16x32_f16(am[mt], bn[nt], acc[mt][nt], 0, 0, 0);
      __syncthreads();  // drains this iter's stage loads (overlapped with compute)
      cur ^= 1;
    }

    // ---- register-only epilogue for tile t (overlaps next tile's loads) ----
    {
      int lin = lin0 + t;
      int ym = lin / NXB;
      int xn = lin - ym * NXB;
      const long arow = (long)ym * 128;
#pragma unroll
      for (int mt = 0; mt < 4; mt++) {
#pragma unroll
        for (int nt = 0; nt < 4; nt++) {
          int c = xn * 128 + wn * 64 + nt * 16 + col0;
          float bc = bias[c];
#pragma unroll
          for (int reg = 0; reg < 4; reg++) {
            long m = arow + wm * 64 + mt * 16 + quad * 4 + reg;
            float v = acc[mt][nt][reg] + bc;
            if (MODE == 0) {
              int which = c / 384;
              int rem = c - which * 384;
              int hh = rem >> 5, d = rem & 31;
              long b = m >> 6;
              long n = m & 63;
              ((f16*)out)[(((long)which * (NWIN * NH) + b * NH + hh) * 64 + n) * 32 + d] = (f16)v;
            } else {
              ((float*)out)[m * 384 + c] = v;
            }
          }
          acc[mt][nt] = (f32x4){0.f, 0.f, 0.f, 0.f};
        }
      }
    }
  }
}

// ---------------- fused window attention: one block per (b,h) ----------------
__global__ __launch_bounds__(256) void k_attn(const f16* __restrict__ qkv,
                                              const float* __restrict__ mask,
                                              const float* __restrict__ bias,
                                              const float* __restrict__ lsc,
                                              f16* __restrict__ aout) {
  __shared__ f16 qs[64 * 32];
  __shared__ f16 ks[64 * 32];
  __shared__ f16 vt[32 * 72];   // V^T, padded
  __shared__ float sm[64 * 64]; // bias + mask
  __shared__ f16 ps[64 * 72];   // P, padded

  const int bh = blockIdx.x;
  const int b = bh / NH;
  const int h = bh - b * NH;
  const int w = b & 1023;  // b % nW
  const int tid = threadIdx.x;
  const int lane = tid & 63, wid = tid >> 6;

  const long HB = (long)NWIN * NH * 64 * 32;
  const f16* qg = qkv + (long)bh * 2048;

  // cooperative load q,k,v (each 64x32 f16 = 4KB); 8 f16 per thread
  f16x8 qv = ((const f16x8*)qg)[tid];
  f16x8 kv = ((const f16x8*)(qg + HB))[tid];
  f16x8 vv = ((const f16x8*)(qg + 2 * HB))[tid];

  // row norms (4 threads per row of 32)
  float ssq = 0.f, ssk = 0.f;
#pragma unroll
  for (int j = 0; j < 8; j++) {
    float xq = (float)qv[j]; ssq += xq * xq;
    float xk = (float)kv[j]; ssk += xk * xk;
  }
  ssq += __shfl_xor(ssq, 1); ssq += __shfl_xor(ssq, 2);
  ssk += __shfl_xor(ssk, 1); ssk += __shfl_xor(ssk, 2);
  float lscale = __expf(fminf(lsc[h], 4.6051701860f));  // exp(min(ls, log(100)))
  float qsc = lscale / fmaxf(sqrtf(ssq), 1e-12f);
  float ksc = 1.f / fmaxf(sqrtf(ssk), 1e-12f);

  f16x8 qn, kn;
#pragma unroll
  for (int j = 0; j < 8; j++) {
    qn[j] = (f16)((float)qv[j] * qsc);
    kn[j] = (f16)((float)kv[j] * ksc);
  }
  ((f16x8*)qs)[tid] = qn;
  ((f16x8*)ks)[tid] = kn;
  {
    int vrow = tid >> 2, d0 = (tid & 3) * 8;
#pragma unroll
    for (int j = 0; j < 8; j++) vt[(d0 + j) * 72 + vrow] = vv[j];
  }
  // stage bias+mask sum into LDS (fp32)
  {
    const float4* bp = (const float4*)(bias + (long)h * 4096);
    const float4* mp = (const float4*)(mask + (long)w * 4096);
#pragma unroll
    for (int j = 0; j < 4; j++) {
      int i4 = tid + 256 * j;
      float4 bb = bp[i4];
      float4 mm = mp[i4];
      bb.x += mm.x; bb.y += mm.y; bb.z += mm.z; bb.w += mm.w;
      ((float4*)sm)[i4] = bb;
    }
  }
  __syncthreads();

  const int col0 = lane & 15, quad = lane >> 4;
  // S = q_hat * k_hat^T  (wave wid owns query rows [16*wid, 16*wid+16))
  f16x8 aq = *(const f16x8*)&qs[(wid * 16 + col0) * 32 + quad * 8];
  f32x4 s[4];
#pragma unroll
  for (int nt = 0; nt < 4; nt++) {
    f16x8 bk = *(const f16x8*)&ks[(nt * 16 + col0) * 32 + quad * 8];
    f32x4 z = {};
    s[nt] = __builtin_amdgcn_mfma_f32_16x16x32_f16(aq, bk, z, 0, 0, 0);
  }

  float rinv[4];
#pragma unroll
  for (int reg = 0; reg < 4; reg++) {
    int r = wid * 16 + quad * 4 + reg;
    float m_ = -1e30f;
#pragma unroll
    for (int nt = 0; nt < 4; nt++) {
      s[nt][reg] += sm[r * 64 + nt * 16 + col0];
      m_ = fmaxf(m_, s[nt][reg]);
    }
    m_ = fmaxf(m_, __shfl_xor(m_, 1));
    m_ = fmaxf(m_, __shfl_xor(m_, 2));
    m_ = fmaxf(m_, __shfl_xor(m_, 4));
    m_ = fmaxf(m_, __shfl_xor(m_, 8));
    float l_ = 0.f;
#pragma unroll
    for (int nt = 0; nt < 4; nt++) {
      float p = __expf(s[nt][reg] - m_);
      s[nt][reg] = p;
      l_ += p;
    }
    l_ += __shfl_xor(l_, 1);
    l_ += __shfl_xor(l_, 2);
    l_ += __shfl_xor(l_, 4);
    l_ += __shfl_xor(l_, 8);
    rinv[reg] = 1.f / l_;
#pragma unroll
    for (int nt = 0; nt < 4; nt++) ps[r * 72 + nt * 16 + col0] = (f16)s[nt][reg];
  }
  __syncthreads();

  // O = P * V   (K=64 keys in 2 steps; N=32 dims in 2 tiles)
  f32x4 o[2] = {};
#pragma unroll
  for (int kkk = 0; kkk < 2; kkk++) {
    f16x8 ap = *(const f16x8*)&ps[(wid * 16 + col0) * 72 + kkk * 32 + quad * 8];
#pragma unroll
    for (int nt = 0; nt < 2; nt++) {
      f16x8 bv = *(const f16x8*)&vt[(nt * 16 + col0) * 72 + kkk * 32 + quad * 8];
      o[nt] = __builtin_amdgcn_mfma_f32_16x16x32_f16(ap, bv, o[nt], 0, 0, 0);
    }
  }
#pragma unroll
  for (int nt = 0; nt < 2; nt++)
#pragma unroll
    for (int reg = 0; reg < 4; reg++) {
      int r = wid * 16 + quad * 4 + reg;
      int d = nt * 16 + col0;
      float v = o[nt][reg] * rinv[reg];
      aout[((long)b * 64 + r) * 384 + h * 32 + d] = (f16)v;
    }
}

// ---------------- launch ----------------

extern "C" void kernel_launch(void* const* d_in, const int* in_sizes, int n_in,
                              void* d_out, int out_size, void* d_ws, size_t ws_size,
                              hipStream_t stream) {
  const float* x      = (const float*)d_in[0];
  const float* mask   = (const float*)d_in[1];
  const float* qkv_w  = (const float*)d_in[2];
  const float* qkv_b  = (const float*)d_in[3];
  const float* proj_w = (const float*)d_in[4];
  const float* proj_b = (const float*)d_in[5];
  const float* lsc    = (const float*)d_in[6];
  const float* cpb_w1 = (const float*)d_in[7];
  const float* cpb_b1 = (const float*)d_in[8];
  const float* cpb_w2 = (const float*)d_in[9];
  const float* table  = (const float*)d_in[10];
  const int* ridx     = (const int*)d_in[11];
  float* out = (float*)d_out;

  char* ws = (char*)d_ws;
  const long NQKV = (long)3 * NWIN * NH * 64 * 32;  // 301,989,888 f16
  f16* qkvbuf = (f16*)ws;                                            // 603,979,776 B
  f16* xh     = (f16*)(ws + NQKV * 2);                               // 201,326,592 B
  f16* aoutbuf = xh;  // alias: xh is dead once qkv gemm has run
  f16* wtq    = (f16*)(ws + NQKV * 2 + 201326592L);                  // 884,736 B
  f16* wtp    = (f16*)(ws + NQKV * 2 + 201326592L + 884736L);        // 294,912 B
  float* biasbuf = (float*)(ws + NQKV * 2 + 201326592L + 884736L + 294912L);  // 196,608 B

  // prep
  k_cvt_x<<<4096, 256, 0, stream>>>(x, xh, 100663296L / 4);
  k_transpose<<<(1152 * 384) / 256, 256, 0, stream>>>(qkv_w, wtq, 384, 1152);
  k_transpose<<<(384 * 384) / 256, 256, 0, stream>>>(proj_w, wtp, 384, 384);
  k_cpb<<<64, 64, 0, stream>>>(table, ridx, cpb_w1, cpb_b1, cpb_w2, biasbuf);

  // qkv gemm: M=262144, K=384, N=1152 -> 18432 tiles = 768 blocks x 24
  k_gemm<0, 9, 24><<<768, 256, 0, stream>>>(xh, wtq, qkv_b, qkvbuf, 384);

  // fused attention per (b,h)
  k_attn<<<NWIN * NH, 256, 0, stream>>>(qkvbuf, mask, biasbuf, lsc, aoutbuf);

  // proj gemm: M=262144, K=384, N=384 -> 6144 tiles = 768 blocks x 8
  k_gemm<1, 3, 8><<<768, 256, 0, stream>>>(aoutbuf, wtp, proj_b, out, 384);
}

// Round 4
// 1504.763 us; speedup vs baseline: 1.0572x; 1.0572x over previous
//
#include <hip/hip_runtime.h>
#include <hip/hip_fp16.h>

typedef _Float16 f16;
typedef _Float16 f16x8 __attribute__((ext_vector_type(8)));
typedef _Float16 f16x4 __attribute__((ext_vector_type(4)));
typedef float f32x4 __attribute__((ext_vector_type(4)));

#define NH 12
#define NWIN 4096
// tokens per window = 64, head dim = 32, DIM = 384, qkv N = 1152

__device__ __forceinline__ void gload16(const void* g, void* l) {
  __builtin_amdgcn_global_load_lds(
      (const __attribute__((address_space(1))) void*)g,
      (__attribute__((address_space(3))) void*)l, 16, 0, 0);
}

// ---------------- prep kernels ----------------

__global__ __launch_bounds__(256) void k_cvt_x(const float* __restrict__ in,
                                               f16* __restrict__ out, long n4) {
  long i = (long)blockIdx.x * 256 + threadIdx.x;
  long stride = (long)gridDim.x * 256;
  for (; i < n4; i += stride) {
    float4 v = ((const float4*)in)[i];
    f16x4 o = {(f16)v.x, (f16)v.y, (f16)v.z, (f16)v.w};
    ((f16x4*)out)[i] = o;
  }
}

// out[n*K + k] = in[k*N + n]  (cast to f16)
__global__ __launch_bounds__(256) void k_transpose(const float* __restrict__ in,
                                                   f16* __restrict__ out, int K, int N) {
  long i = (long)blockIdx.x * 256 + threadIdx.x;
  if (i >= (long)K * N) return;
  int n = (int)(i / K);
  int k = (int)(i - (long)n * K);
  out[i] = (f16)in[(long)k * N + n];
}

// continuous position bias: bias[h][p] = 16*sigmoid( MLP(table[rel_pos_index[p]]) . w2[:,h] )
__global__ __launch_bounds__(64) void k_cpb(const float* __restrict__ table,
                                            const int* __restrict__ ridx,
                                            const float* __restrict__ w1,
                                            const float* __restrict__ b1,
                                            const float* __restrict__ w2,
                                            float* __restrict__ biasout) {
  int p = blockIdx.x * 64 + threadIdx.x;  // 0..4095
  int idx = ridx[p];
  float t0 = table[idx * 2], t1 = table[idx * 2 + 1];
  float acc[NH] = {};
  for (int u = 0; u < 512; u++) {
    float hv = fmaxf(t0 * w1[u] + t1 * w1[512 + u] + b1[u], 0.f);
#pragma unroll
    for (int h = 0; h < NH; h++) acc[h] += hv * w2[u * NH + h];
  }
  for (int h = 0; h < NH; h++) biasout[h * 4096 + p] = 16.f / (1.f + __expf(-acc[h]));
}

// ---------------- persistent GEMM: C[M x N] = A[M x K] * Bt[N x K]^T + bias -------
// Persistent blocks, GRID-STRIDED tile order: tile t of block b is
// lin = t*GRID + b. At any time step all blocks process a contiguous lin-window
// (identical sequence to the non-persistent R2 dispatch), so the XCD swizzle
// decode keeps all 9 xn-tiles of a ym-row concurrent on ONE XCD -> A-panel
// re-reads hit L2/L3 (FETCH ~104MB, vs 1GB with block-contiguous order, R3).
// The 2-phase double-buffer flows ACROSS tile boundaries: during tile t's last
// k-step we stage tile t+1's k=0 chunk, so the prologue drain is paid once per
// block and the register-only epilogue overlaps the next tile's in-flight loads.
// MODE 0: qkv gemm (N=1152), f16 scatter out to [3][b*12+h][64][32]
// MODE 1: proj gemm (N=384), fp32 out row-major [M][384]
template <int MODE, int NXB, int TPB, int GRID>
__global__ __launch_bounds__(256, 3) void k_gemm(const f16* __restrict__ A,
                                                 const f16* __restrict__ Bt,
                                                 const float* __restrict__ bias,
                                                 void* __restrict__ out, int K) {
  __shared__ f16 smem[2 * 8192];  // [buf][As 4096 f16 | Bs 4096 f16]
  const int tid = threadIdx.x;
  const int lane = tid & 63, wid = tid >> 6;
  const int wm = wid & 1, wn = wid >> 1;
  const int quad = lane >> 4, col0 = lane & 15;
  const int bid = blockIdx.x;

  // staging geometry: wave wid covers rows [wid*32, wid*32+32), 4 lanes/row
  const int r0 = wid * 32 + (lane >> 2);
  const int co0 = (lane & 3) * 8;
  const int ldsoff = (wid * 32) * 32;

  auto decode = [&](int t, int& ym, int& xn) {
    int lin = t * GRID + bid;
    int idx = lin % (NXB * 8);
    xn = idx >> 3;
    ym = (lin / (NXB * 8)) * 8 + (idx & 7);
  };

  auto rows_of = [&](int t, long& ar, long& br) {
    int ym, xn;
    decode(t, ym, xn);
    ar = (long)ym * 128;
    br = (long)xn * 128;
  };

  auto stage = [&](int buf, long ar, long br, int kk) {
#pragma unroll
    for (int j = 0; j < 2; j++) {
      gload16(A + (ar + r0 + j * 16) * K + co0 + kk,
              smem + buf * 8192 + ldsoff + j * 16 * 32);
      gload16(Bt + (br + r0 + j * 16) * K + co0 + kk,
              smem + buf * 8192 + 4096 + ldsoff + j * 16 * 32);
    }
  };

  f32x4 acc[4][4] = {};
  long ar, br;
  rows_of(0, ar, br);
  stage(0, ar, br, 0);
  __syncthreads();  // prologue drain (full latency, paid once per block)
  int cur = 0;

#pragma unroll 1
  for (int t = 0; t < TPB; t++) {
    rows_of(t, ar, br);
#pragma unroll 1
    for (int kk = 0; kk < K; kk += 32) {
      if (kk + 32 < K) {
        stage(cur ^ 1, ar, br, kk + 32);
      } else if (t + 1 < TPB) {
        long a2, b2;
        rows_of(t + 1, a2, b2);
        stage(cur ^ 1, a2, b2, 0);  // cross-tile prefetch: pipeline never drains
      }
      const f16* As = smem + cur * 8192;
      const f16* Bs = As + 4096;
      f16x8 am[4], bn[4];
#pragma unroll
      for (int tt = 0; tt < 4; tt++) {
        am[tt] = *(const f16x8*)&As[(wm * 64 + tt * 16 + col0) * 32 + quad * 8];
        bn[tt] = *(const f16x8*)&Bs[(wn * 64 + tt * 16 + col0) * 32 + quad * 8];
      }
#pragma unroll
      for (int mt = 0; mt < 4; mt++)
#pragma unroll
        for (int nt = 0; nt < 4; nt++)
          acc[mt][nt] = __builtin_amdgcn_mfma_f32_16x16x32_f16(am[mt], bn[nt], acc[mt][nt], 0, 0, 0);
      __syncthreads();  // drains this iter's stage loads (overlapped with compute)
      cur ^= 1;
    }

    // ---- register-only epilogue for tile t (overlaps next tile's loads) ----
    {
      int ym, xn;
      decode(t, ym, xn);
      const long arow = (long)ym * 128;
#pragma unroll
      for (int mt = 0; mt < 4; mt++) {
#pragma unroll
        for (int nt = 0; nt < 4; nt++) {
          int c = xn * 128 + wn * 64 + nt * 16 + col0;
          float bc = bias[c];
#pragma unroll
          for (int reg = 0; reg < 4; reg++) {
            long m = arow + wm * 64 + mt * 16 + quad * 4 + reg;
            float v = acc[mt][nt][reg] + bc;
            if (MODE == 0) {
              int which = c / 384;
              int rem = c - which * 384;
              int hh = rem >> 5, d = rem & 31;
              long b = m >> 6;
              long n = m & 63;
              ((f16*)out)[(((long)which * (NWIN * NH) + b * NH + hh) * 64 + n) * 32 + d] = (f16)v;
            } else {
              ((float*)out)[m * 384 + c] = v;
            }
          }
          acc[mt][nt] = (f32x4){0.f, 0.f, 0.f, 0.f};
        }
      }
    }
  }
}

// ---------------- fused window attention: one block per (b,h) ----------------
__global__ __launch_bounds__(256) void k_attn(const f16* __restrict__ qkv,
                                              const float* __restrict__ mask,
                                              const float* __restrict__ bias,
                                              const float* __restrict__ lsc,
                                              f16* __restrict__ aout) {
  __shared__ f16 qs[64 * 32];
  __shared__ f16 ks[64 * 32];
  __shared__ f16 vt[32 * 72];   // V^T, padded
  __shared__ float sm[64 * 64]; // bias + mask
  __shared__ f16 ps[64 * 72];   // P, padded

  const int bh = blockIdx.x;
  const int b = bh / NH;
  const int h = bh - b * NH;
  const int w = b & 1023;  // b % nW
  const int tid = threadIdx.x;
  const int lane = tid & 63, wid = tid >> 6;

  const long HB = (long)NWIN * NH * 64 * 32;
  const f16* qg = qkv + (long)bh * 2048;

  // cooperative load q,k,v (each 64x32 f16 = 4KB); 8 f16 per thread
  f16x8 qv = ((const f16x8*)qg)[tid];
  f16x8 kv = ((const f16x8*)(qg + HB))[tid];
  f16x8 vv = ((const f16x8*)(qg + 2 * HB))[tid];

  // row norms (4 threads per row of 32)
  float ssq = 0.f, ssk = 0.f;
#pragma unroll
  for (int j = 0; j < 8; j++) {
    float xq = (float)qv[j]; ssq += xq * xq;
    float xk = (float)kv[j]; ssk += xk * xk;
  }
  ssq += __shfl_xor(ssq, 1); ssq += __shfl_xor(ssq, 2);
  ssk += __shfl_xor(ssk, 1); ssk += __shfl_xor(ssk, 2);
  float lscale = __expf(fminf(lsc[h], 4.6051701860f));  // exp(min(ls, log(100)))
  float qsc = lscale / fmaxf(sqrtf(ssq), 1e-12f);
  float ksc = 1.f / fmaxf(sqrtf(ssk), 1e-12f);

  f16x8 qn, kn;
#pragma unroll
  for (int j = 0; j < 8; j++) {
    qn[j] = (f16)((float)qv[j] * qsc);
    kn[j] = (f16)((float)kv[j] * ksc);
  }
  ((f16x8*)qs)[tid] = qn;
  ((f16x8*)ks)[tid] = kn;
  {
    int vrow = tid >> 2, d0 = (tid & 3) * 8;
#pragma unroll
    for (int j = 0; j < 8; j++) vt[(d0 + j) * 72 + vrow] = vv[j];
  }
  // stage bias+mask sum into LDS (fp32)
  {
    const float4* bp = (const float4*)(bias + (long)h * 4096);
    const float4* mp = (const float4*)(mask + (long)w * 4096);
#pragma unroll
    for (int j = 0; j < 4; j++) {
      int i4 = tid + 256 * j;
      float4 bb = bp[i4];
      float4 mm = mp[i4];
      bb.x += mm.x; bb.y += mm.y; bb.z += mm.z; bb.w += mm.w;
      ((float4*)sm)[i4] = bb;
    }
  }
  __syncthreads();

  const int col0 = lane & 15, quad = lane >> 4;
  // S = q_hat * k_hat^T  (wave wid owns query rows [16*wid, 16*wid+16))
  f16x8 aq = *(const f16x8*)&qs[(wid * 16 + col0) * 32 + quad * 8];
  f32x4 s[4];
#pragma unroll
  for (int nt = 0; nt < 4; nt++) {
    f16x8 bk = *(const f16x8*)&ks[(nt * 16 + col0) * 32 + quad * 8];
    f32x4 z = {};
    s[nt] = __builtin_amdgcn_mfma_f32_16x16x32_f16(aq, bk, z, 0, 0, 0);
  }

  float rinv[4];
#pragma unroll
  for (int reg = 0; reg < 4; reg++) {
    int r = wid * 16 + quad * 4 + reg;
    float m_ = -1e30f;
#pragma unroll
    for (int nt = 0; nt < 4; nt++) {
      s[nt][reg] += sm[r * 64 + nt * 16 + col0];
      m_ = fmaxf(m_, s[nt][reg]);
    }
    m_ = fmaxf(m_, __shfl_xor(m_, 1));
    m_ = fmaxf(m_, __shfl_xor(m_, 2));
    m_ = fmaxf(m_, __shfl_xor(m_, 4));
    m_ = fmaxf(m_, __shfl_xor(m_, 8));
    float l_ = 0.f;
#pragma unroll
    for (int nt = 0; nt < 4; nt++) {
      float p = __expf(s[nt][reg] - m_);
      s[nt][reg] = p;
      l_ += p;
    }
    l_ += __shfl_xor(l_, 1);
    l_ += __shfl_xor(l_, 2);
    l_ += __shfl_xor(l_, 4);
    l_ += __shfl_xor(l_, 8);
    rinv[reg] = 1.f / l_;
#pragma unroll
    for (int nt = 0; nt < 4; nt++) ps[r * 72 + nt * 16 + col0] = (f16)s[nt][reg];
  }
  __syncthreads();

  // O = P * V   (K=64 keys in 2 steps; N=32 dims in 2 tiles)
  f32x4 o[2] = {};
#pragma unroll
  for (int kkk = 0; kkk < 2; kkk++) {
    f16x8 ap = *(const f16x8*)&ps[(wid * 16 + col0) * 72 + kkk * 32 + quad * 8];
#pragma unroll
    for (int nt = 0; nt < 2; nt++) {
      f16x8 bv = *(const f16x8*)&vt[(nt * 16 + col0) * 72 + kkk * 32 + quad * 8];
      o[nt] = __builtin_amdgcn_mfma_f32_16x16x32_f16(ap, bv, o[nt], 0, 0, 0);
    }
  }
#pragma unroll
  for (int nt = 0; nt < 2; nt++)
#pragma unroll
    for (int reg = 0; reg < 4; reg++) {
      int r = wid * 16 + quad * 4 + reg;
      int d = nt * 16 + col0;
      float v = o[nt][reg] * rinv[reg];
      aout[((long)b * 64 + r) * 384 + h * 32 + d] = (f16)v;
    }
}

// ---------------- launch ----------------

extern "C" void kernel_launch(void* const* d_in, const int* in_sizes, int n_in,
                              void* d_out, int out_size, void* d_ws, size_t ws_size,
                              hipStream_t stream) {
  const float* x      = (const float*)d_in[0];
  const float* mask   = (const float*)d_in[1];
  const float* qkv_w  = (const float*)d_in[2];
  const float* qkv_b  = (const float*)d_in[3];
  const float* proj_w = (const float*)d_in[4];
  const float* proj_b = (const float*)d_in[5];
  const float* lsc    = (const float*)d_in[6];
  const float* cpb_w1 = (const float*)d_in[7];
  const float* cpb_b1 = (const float*)d_in[8];
  const float* cpb_w2 = (const float*)d_in[9];
  const float* table  = (const float*)d_in[10];
  const int* ridx     = (const int*)d_in[11];
  float* out = (float*)d_out;

  char* ws = (char*)d_ws;
  const long NQKV = (long)3 * NWIN * NH * 64 * 32;  // 301,989,888 f16
  f16* qkvbuf = (f16*)ws;                                            // 603,979,776 B
  f16* xh     = (f16*)(ws + NQKV * 2);                               // 201,326,592 B
  f16* aoutbuf = xh;  // alias: xh is dead once qkv gemm has run
  f16* wtq    = (f16*)(ws + NQKV * 2 + 201326592L);                  // 884,736 B
  f16* wtp    = (f16*)(ws + NQKV * 2 + 201326592L + 884736L);        // 294,912 B
  float* biasbuf = (float*)(ws + NQKV * 2 + 201326592L + 884736L + 294912L);  // 196,608 B

  // prep
  k_cvt_x<<<4096, 256, 0, stream>>>(x, xh, 100663296L / 4);
  k_transpose<<<(1152 * 384) / 256, 256, 0, stream>>>(qkv_w, wtq, 384, 1152);
  k_transpose<<<(384 * 384) / 256, 256, 0, stream>>>(proj_w, wtp, 384, 384);
  k_cpb<<<64, 64, 0, stream>>>(table, ridx, cpb_w1, cpb_b1, cpb_w2, biasbuf);

  // qkv gemm: M=262144, K=384, N=1152 -> 18432 tiles = 768 blocks x 24 (grid-strided)
  k_gemm<0, 9, 24, 768><<<768, 256, 0, stream>>>(xh, wtq, qkv_b, qkvbuf, 384);

  // fused attention per (b,h)
  k_attn<<<NWIN * NH, 256, 0, stream>>>(qkvbuf, mask, biasbuf, lsc, aoutbuf);

  // proj gemm: M=262144, K=384, N=384 -> 6144 tiles = 768 blocks x 8 (grid-strided)
  k_gemm<1, 3, 8, 768><<<768, 256, 0, stream>>>(aoutbuf, wtp, proj_b, out, 384);
}